// Round 17
// baseline (89.782 us; speedup 1.0000x reference)
//
#include <hip/hip_runtime.h>
#include <hip/hip_bf16.h>
#include <math.h>

// Problem constants (Mask2Former pixel decoder / MS-deformable attention)
#define BB 4
#define SEQ 5376
#define DD 256
#define NH 8
#define NL 3
#define NP 4
#define DH 32
#define MTOT (BB * SEQ)          // 21504 rows for all GEMMs

typedef __attribute__((ext_vector_type(8))) short bf16x8;
typedef __attribute__((ext_vector_type(4))) float f32x4;
typedef __attribute__((ext_vector_type(2))) float f32x2;

#define GLD_LDS16(src, dst) __builtin_amdgcn_global_load_lds( \
    (const __attribute__((address_space(1))) void*)(src),     \
    (__attribute__((address_space(3))) void*)(dst), 16, 0, 0)

__device__ __forceinline__ ushort f2b(float f) {
    __hip_bfloat16 h = __float2bfloat16(f);
    return *reinterpret_cast<ushort*>(&h);
}

// ---------------------------------------------------------------------------
// Fused prep: blocks [0,800] transpose weights -> Wt[800][256] bf16 (+bias
// combine at block 800); blocks [801, 801+2048) convert hidden -> bf16 and
// (hidden+pos) -> bf16 (grid-stride).
// ---------------------------------------------------------------------------
__global__ __launch_bounds__(256) void prep_all(
    const float* __restrict__ hidden, const float* __restrict__ pos,
    const float* __restrict__ Wv, const float* __restrict__ Wo,
    const float* __restrict__ Wa, const float* __restrict__ Wout,
    const float* __restrict__ bo, const float* __restrict__ ba,
    ushort4* __restrict__ hb, ushort4* __restrict__ hsb,
    ushort* __restrict__ Wt, float* __restrict__ bcomb, int n4) {
    int bid = blockIdx.x;
    int tid = threadIdx.x;
    if (bid <= 800) {
        if (bid == 800) {
            for (int i = tid; i < 288; i += 256)
                bcomb[i] = (i < 192) ? bo[i] : ba[i - 192];
            return;
        }
        int row = bid;
        const float* src;
        int N, n;
        if (row < 256)      { src = Wv;   N = 256; n = row; }
        else if (row < 448) { src = Wo;   N = 192; n = row - 256; }
        else if (row < 544) { src = Wa;   N = 96;  n = row - 448; }
        else                { src = Wout; N = 256; n = row - 544; }
        float v = src[(size_t)tid * N + n];
        Wt[(size_t)row * 256 + tid] = f2b(v);
        return;
    }
    // activation conversion
    const float4* h4 = (const float4*)hidden;
    const float4* p4 = (const float4*)pos;
    int i = (bid - 801) * 256 + tid;
    int stride = (gridDim.x - 801) * 256;
    for (; i < n4; i += stride) {
        float4 a = h4[i], b = p4[i];
        ushort4 ua, us;
        ua.x = f2b(a.x); ua.y = f2b(a.y); ua.z = f2b(a.z); ua.w = f2b(a.w);
        us.x = f2b(a.x + b.x); us.y = f2b(a.y + b.y);
        us.z = f2b(a.z + b.z); us.w = f2b(a.w + b.w);
        hb[i] = ua;
        hsb[i] = us;
    }
}

// ---------------------------------------------------------------------------
// Dual bf16 MFMA GEMM (one dispatch = value GEMM + comb GEMM for grid fill).
// Blocks [0,336): value = hb @ Wv^T + bv -> bf16 HEAD-MAJOR [h][row][32ch].
// Blocks [336,840): comb = hsb @ Wcomb^T + bcomb -> fp32, N=288.
// BM=128, BN=128, BK=64; global_load_lds staging, chunk-XOR swizzle both
// sides (R13-proven). 256 thr = 4 waves 2x2; 32 MFMA/wave per barrier pair.
// ---------------------------------------------------------------------------
__global__ __launch_bounds__(256) void gemm_dual(
    const ushort* __restrict__ hb, const ushort* __restrict__ hsb,
    const ushort* __restrict__ Wv_t, const ushort* __restrict__ Wcomb_t,
    const float* __restrict__ bv, const float* __restrict__ bcomb,
    ushort* __restrict__ value_bf, float* __restrict__ comb) {
    const int K = 256, BK = 64;
    __shared__ ushort As[128 * 64];
    __shared__ ushort Bs[128 * 64];

    int b = blockIdx.x;
    const ushort* A;
    const ushort* W;
    const float* bias;
    int bn, bm, N;
    bool obf;
    if (b < 336) {
        A = hb;  W = Wv_t;    bias = bv;    N = 256; obf = true;
        bn = (b & 1) * 128;   bm = (b >> 1) * 128;
    } else {
        int bb = b - 336;
        A = hsb; W = Wcomb_t; bias = bcomb; N = 288; obf = false;
        bn = (bb % 3) * 128;  bm = (bb / 3) * 128;
    }

    int tid = threadIdx.x;
    int lane = tid & 63;
    int wid = tid >> 6;
    int wr = wid >> 1, wc = wid & 1;
    int lr = lane & 15;
    int kg = lane >> 4;

    f32x4 acc[4][4] = {};

    for (int k0 = 0; k0 < K; k0 += BK) {
        #pragma unroll
        for (int c = 0; c < 4; c++) {
            int e = tid + 256 * c;           // chunk id 0..1023
            int row = e >> 3;
            int ch = e & 7;
            int gch = ch ^ (row & 7);
            GLD_LDS16(A + (size_t)(bm + row) * K + k0 + 8 * gch, &As[e * 8]);
            GLD_LDS16(W + (size_t)(bn + row) * K + k0 + 8 * gch, &Bs[e * 8]);
        }
        __syncthreads();
        #pragma unroll
        for (int ks = 0; ks < 2; ks++) {
            bf16x8 af[4], bfr[4];
            #pragma unroll
            for (int mf = 0; mf < 4; mf++) {
                int R = wr * 64 + mf * 16 + lr;
                int sc = (ks * 4 + kg) ^ (R & 7);
                af[mf] = *(bf16x8*)&As[R * 64 + sc * 8];
            }
            #pragma unroll
            for (int nf = 0; nf < 4; nf++) {
                int R = wc * 64 + nf * 16 + lr;
                int sc = (ks * 4 + kg) ^ (R & 7);
                bfr[nf] = *(bf16x8*)&Bs[R * 64 + sc * 8];
            }
            #pragma unroll
            for (int mf = 0; mf < 4; mf++)
                #pragma unroll
                for (int nf = 0; nf < 4; nf++)
                    acc[mf][nf] = __builtin_amdgcn_mfma_f32_16x16x32_bf16(
                        af[mf], bfr[nf], acc[mf][nf], 0, 0, 0);
        }
        __syncthreads();
    }

    #pragma unroll
    for (int nf = 0; nf < 4; nf++) {
        int gc = bn + wc * 64 + nf * 16 + lr;
        if (gc >= N) continue;
        float bvv = bias[gc];
        #pragma unroll
        for (int mf = 0; mf < 4; mf++) {
            int gr0 = bm + wr * 64 + mf * 16 + kg * 4;
            #pragma unroll
            for (int r = 0; r < 4; r++) {
                float v = acc[mf][nf][r] + bvv;
                if (obf) {
                    // head-major scatter: [h][row][32ch]
                    int hh = gc >> 5, cc = gc & 31;
                    value_bf[(size_t)hh * ((size_t)MTOT * 32)
                             + (size_t)(gr0 + r) * 32 + cc] = f2b(v);
                } else {
                    comb[(size_t)(gr0 + r) * 288 + gc] = v;
                }
            }
        }
    }
}

// ---------------------------------------------------------------------------
// Output GEMM: out = sampb @ Wout^T + bout, N=256, fp32 out.
// BM=128, BN=64 (672 blocks for grid fill), BK=64; gld_lds + XOR swizzle.
// ---------------------------------------------------------------------------
__global__ __launch_bounds__(256) void gemm_out(
    const ushort* __restrict__ A, const ushort* __restrict__ Wt,
    const float* __restrict__ bias, float* __restrict__ C) {
    const int K = 256, BK = 64;
    __shared__ ushort As[128 * 64];
    __shared__ ushort Bs[64 * 64];
    int bm = blockIdx.y * 128;
    int bn = blockIdx.x * 64;
    int tid = threadIdx.x;
    int lane = tid & 63;
    int wid = tid >> 6;
    int wr = wid >> 1, wc = wid & 1;
    int lr = lane & 15;
    int kg = lane >> 4;

    f32x4 acc[4][2] = {};

    for (int k0 = 0; k0 < K; k0 += BK) {
        #pragma unroll
        for (int c = 0; c < 4; c++) {
            int e = tid + 256 * c;
            int row = e >> 3;
            int ch = e & 7;
            int gch = ch ^ (row & 7);
            GLD_LDS16(A + (size_t)(bm + row) * K + k0 + 8 * gch, &As[e * 8]);
        }
        #pragma unroll
        for (int c = 0; c < 2; c++) {
            int e = tid + 256 * c;           // 0..511
            int row = e >> 3;                // 0..63
            int ch = e & 7;
            int gch = ch ^ (row & 7);
            GLD_LDS16(Wt + (size_t)(bn + row) * K + k0 + 8 * gch, &Bs[e * 8]);
        }
        __syncthreads();
        #pragma unroll
        for (int ks = 0; ks < 2; ks++) {
            bf16x8 af[4], bfr[2];
            #pragma unroll
            for (int mf = 0; mf < 4; mf++) {
                int R = wr * 64 + mf * 16 + lr;
                int sc = (ks * 4 + kg) ^ (R & 7);
                af[mf] = *(bf16x8*)&As[R * 64 + sc * 8];
            }
            #pragma unroll
            for (int nf = 0; nf < 2; nf++) {
                int R = wc * 32 + nf * 16 + lr;
                int sc = (ks * 4 + kg) ^ (R & 7);
                bfr[nf] = *(bf16x8*)&Bs[R * 64 + sc * 8];
            }
            #pragma unroll
            for (int mf = 0; mf < 4; mf++)
                #pragma unroll
                for (int nf = 0; nf < 2; nf++)
                    acc[mf][nf] = __builtin_amdgcn_mfma_f32_16x16x32_bf16(
                        af[mf], bfr[nf], acc[mf][nf], 0, 0, 0);
        }
        __syncthreads();
    }

    #pragma unroll
    for (int nf = 0; nf < 2; nf++) {
        int gc = bn + wc * 32 + nf * 16 + lr;
        float bvv = bias[gc];
        #pragma unroll
        for (int mf = 0; mf < 4; mf++) {
            int gr0 = bm + wr * 64 + mf * 16 + kg * 4;
            #pragma unroll
            for (int r = 0; r < 4; r++) {
                C[(size_t)(gr0 + r) * 256 + gc] = acc[mf][nf][r] + bvv;
            }
        }
    }
}

// ---------------------------------------------------------------------------
// Deformable sampling v13: (b,h,chunk)-pinned blocks + l2 slice in LDS.
// Grid = 4b x 21chunk x 8h = 672 blocks, 256 thr (4 waves), 256 q/block.
// Stage: l2 slice of (b,h) = 256 rows x 32ch bf16 = 16 KB, contiguous in
// head-major value; taps 8-11 read it via ds_read_b128 (uniform ~8-way
// banking). Taps 0-7 keep v12's x-pair global path. Per 64-q sub-chunk:
// phase 1 = softmax + tap tables; phase 2 = gather/FMA (8 lanes/query:
// part = x-slot, c4 = channel quad; shfl_xor(4) combines x-parts).
// ---------------------------------------------------------------------------
__device__ __forceinline__ void fma8p(f32x2 acc[4], float wt, uint4 u) {
    f32x2 w2 = {wt, wt};
    f32x2 v0, v1, v2, v3;
    v0[0] = __uint_as_float(u.x << 16); v0[1] = __uint_as_float(u.x & 0xffff0000u);
    v1[0] = __uint_as_float(u.y << 16); v1[1] = __uint_as_float(u.y & 0xffff0000u);
    v2[0] = __uint_as_float(u.z << 16); v2[1] = __uint_as_float(u.z & 0xffff0000u);
    v3[0] = __uint_as_float(u.w << 16); v3[1] = __uint_as_float(u.w & 0xffff0000u);
    acc[0] = __builtin_elementwise_fma(v0, w2, acc[0]);
    acc[1] = __builtin_elementwise_fma(v1, w2, acc[1]);
    acc[2] = __builtin_elementwise_fma(v2, w2, acc[2]);
    acc[3] = __builtin_elementwise_fma(v3, w2, acc[3]);
}

__global__ __launch_bounds__(256) void msda_sample_v13(
    const ushort* __restrict__ value, const float* __restrict__ comb,
    const float* __restrict__ refp, float* __restrict__ attn_out,
    ushort* __restrict__ out) {
    __shared__ ushort l2s[256 * 32];     // 16 KB staged l2 slice of (b,h)
    __shared__ int2   s_idx[64][13];     // per-(q,tap): row offsets (elems)
    __shared__ float4 s_w[64][13];       // (wA_y0, wB_y0, wA_y1, wB_y1)
    int tid = threadIdx.x;
    int blk = blockIdx.x;
    int h     = blk & 7;
    int rest  = blk >> 3;                // 0..83
    int chunk = rest % 21;
    int b     = rest / 21;
    int bq0 = b * SEQ + chunk * 256;     // block's first query (global row)

    // ---- stage l2 slice: contiguous 16 KB ----
    {
        const ushort* l2src = value + (size_t)h * ((size_t)MTOT * 32)
                              + ((size_t)b * SEQ + 5120) * 32;
        #pragma unroll
        for (int c = 0; c < 4; c++) {
            int e = tid + 256 * c;       // 16B chunk id 0..1023
            GLD_LDS16(l2src + e * 8, &l2s[e * 8]);
        }
    }

    int wave = tid >> 6, lane = tid & 63;
    int q8 = lane >> 3;
    int d8 = lane & 7;
    int part = d8 >> 2;                  // x-slot within pair
    int c4 = d8 & 3;                     // channel quad (8 ch)
    const ushort* vbg = value + (size_t)h * ((size_t)MTOT * 32)
                        + part * 32 + c4 * 8;
    int lofs = part * 32 + c4 * 8;       // lane offset into l2s (elems)

    for (int cc = 0; cc < 4; cc++) {
        int q0 = cc * 64;
        // ---- phase 1: softmax + tap setup (64q x 16 slots, 4 passes) ----
        #pragma unroll
        for (int it = 0; it < 4; it++) {
            int t = tid + it * 256;
            int lp = t & 15;
            int q6 = t >> 4;             // 0..63
            int bq = bq0 + q0 + q6;
            bool active = lp < 12;
            const float* crow = comb + (size_t)bq * 288;
            float logit = active ? crow[192 + h * 12 + lp] : -INFINITY;
            float m = logit;
            m = fmaxf(m, __shfl_xor(m, 1, 16));
            m = fmaxf(m, __shfl_xor(m, 2, 16));
            m = fmaxf(m, __shfl_xor(m, 4, 16));
            m = fmaxf(m, __shfl_xor(m, 8, 16));
            float e = active ? expf(logit - m) : 0.f;
            float s = e;
            s += __shfl_xor(s, 1, 16);
            s += __shfl_xor(s, 2, 16);
            s += __shfl_xor(s, 4, 16);
            s += __shfl_xor(s, 8, 16);
            float aw = e / s;
            if (active) {
                attn_out[(size_t)bq * 96 + h * 12 + lp] = aw;
                int l = lp >> 2;
                int Wl = 64 >> l;
                float fW = (float)Wl;
                float rx = refp[(size_t)bq * 6 + 2 * l];
                float ry = refp[(size_t)bq * 6 + 2 * l + 1];
                float ox = crow[h * 24 + lp * 2];
                float oy = crow[h * 24 + lp * 2 + 1];
                float x = rx * fW + ox - 0.5f;
                float y = ry * fW + oy - 0.5f;
                float x0f = floorf(x), y0f = floorf(y);
                float wx = x - x0f, wy = y - y0f;
                int x0 = (int)x0f, y0 = (int)y0f;
                int x1 = x0 + 1, y1 = y0 + 1;
                float vx0 = (x0 >= 0 && x0 < Wl) ? 1.f : 0.f;
                float vx1 = (x1 >= 0 && x1 < Wl) ? 1.f : 0.f;
                float vy0 = (y0 >= 0 && y0 < Wl) ? 1.f : 0.f;   // square
                float vy1 = (y1 >= 0 && y1 < Wl) ? 1.f : 0.f;
                int yc0 = min(max(y0, 0), Wl - 1);
                int yc1 = min(max(y1, 0), Wl - 1);
                int px = min(max(x0, 0), Wl - 2);
                float wxl = (1.f - wx) * vx0;
                float wxh = wx * vx1;
                float wA, wB;
                if (px == x0)      { wA = wxl; wB = wxh; }
                else if (px == x1) { wA = wxh; wB = 0.f; }
                else               { wA = 0.f; wB = wxl; }
                float wy0v = aw * (1.f - wy) * vy0;
                float wy1v = aw * wy * vy1;
                int r0 = yc0 * Wl + px;
                int r1 = yc1 * Wl + px;
                if (l == 2) {
                    // local offsets into staged l2 slice
                    s_idx[q6][lp] = make_int2(r0 * 32, r1 * 32);
                } else {
                    int st = (l == 0) ? 0 : 4096;
                    int rowbase = b * SEQ + st;
                    s_idx[q6][lp] = make_int2((rowbase + r0) * 32,
                                              (rowbase + r1) * 32);
                }
                s_w[q6][lp] = make_float4(wA * wy0v, wB * wy0v,
                                          wA * wy1v, wB * wy1v);
            }
        }
        __syncthreads();   // tables + (first iter) staged slice ready

        // ---- phase 2: 16 queries per wave (2 passes of 8) ----
        #pragma unroll
        for (int p = 0; p < 2; p++) {
            int q6 = wave * 16 + p * 8 + q8;
            int bq = bq0 + q0 + q6;
            f32x2 acc[4] = {{0.f, 0.f}, {0.f, 0.f}, {0.f, 0.f}, {0.f, 0.f}};
            #pragma unroll
            for (int lp = 0; lp < 12; lp++) {
                int2 ii = s_idx[q6][lp];
                float4 ww = s_w[q6][lp];
                float w0 = part ? ww.y : ww.x;
                float w1 = part ? ww.w : ww.z;
                uint4 u0, u1;
                if (lp >= 8) {
                    u0 = *(const uint4*)&l2s[lofs + ii.x];
                    u1 = *(const uint4*)&l2s[lofs + ii.y];
                } else {
                    u0 = *(const uint4*)(vbg + ii.x);
                    u1 = *(const uint4*)(vbg + ii.y);
                }
                fma8p(acc, w0, u0);
                fma8p(acc, w1, u1);
            }
            #pragma unroll
            for (int i = 0; i < 4; i++) {
                acc[i][0] += __shfl_xor(acc[i][0], 4);
                acc[i][1] += __shfl_xor(acc[i][1], 4);
            }
            if (part == 0) {
                bf16x8 o;
                o[0] = (short)f2b(acc[0][0]); o[1] = (short)f2b(acc[0][1]);
                o[2] = (short)f2b(acc[1][0]); o[3] = (short)f2b(acc[1][1]);
                o[4] = (short)f2b(acc[2][0]); o[5] = (short)f2b(acc[2][1]);
                o[6] = (short)f2b(acc[3][0]); o[7] = (short)f2b(acc[3][1]);
                *(bf16x8*)(out + (size_t)bq * 256 + h * 32 + c4 * 8) = o;
            }
        }
        __syncthreads();   // before next chunk overwrites tables
    }
}

// ---------------------------------------------------------------------------
extern "C" void kernel_launch(void* const* d_in, const int* in_sizes, int n_in,
                              void* d_out, int out_size, void* d_ws, size_t ws_size,
                              hipStream_t stream) {
    const float* hidden = (const float*)d_in[0];
    const float* pos    = (const float*)d_in[1];
    const float* refp   = (const float*)d_in[2];
    const float* Wv     = (const float*)d_in[3];
    const float* bv     = (const float*)d_in[4];
    const float* Wo     = (const float*)d_in[5];
    const float* bo     = (const float*)d_in[6];
    const float* Wa     = (const float*)d_in[7];
    const float* ba     = (const float*)d_in[8];
    const float* Wout   = (const float*)d_in[9];
    const float* bout   = (const float*)d_in[10];

    float* out      = (float*)d_out;                       // (B,SEQ,256)
    float* attn_out = out + (size_t)BB * SEQ * DD;         // (B,SEQ,NH,NL,NP)

    const size_t BSD = (size_t)BB * SEQ * DD;              // 5,505,024
    char* w = (char*)d_ws;
    ushort* value_bf = (ushort*)w;  w += BSD * 2;                 // bf16 value (head-major)
    float*  comb     = (float*)w;   w += (size_t)MTOT * 288 * 4;  // off|logits
    ushort* sampb    = (ushort*)w;  w += BSD * 2;                 // bf16 sampled
    ushort* hb       = (ushort*)w;  w += BSD * 2;                 // bf16 hidden
    ushort* hsb      = (ushort*)w;  w += BSD * 2;                 // bf16 hidden+pos
    ushort* Wt       = (ushort*)w;  w += (size_t)800 * 256 * 2;   // bf16 weights^T
    float*  bcomb    = (float*)w;                                 // 288 bias

    // 1. fused prep: weights transpose + activation bf16 conversion
    {
        int n4 = (int)(BSD / 4);
        prep_all<<<801 + 2048, 256, 0, stream>>>(hidden, pos, Wv, Wo, Wa, Wout,
                                                 bo, ba, (ushort4*)hb, (ushort4*)hsb,
                                                 Wt, bcomb, n4);
    }

    const ushort* Wv_t    = Wt;
    const ushort* Wcomb_t = Wt + (size_t)256 * 256;   // rows: 192 Wo + 96 Wa
    const ushort* Wout_t  = Wt + (size_t)544 * 256;

    // 2. fused value+comb GEMMs (840 blocks for grid fill)
    gemm_dual<<<840, 256, 0, stream>>>(hb, hsb, Wv_t, Wcomb_t, bv, bcomb,
                                       value_bf, comb);

    // 3. fused softmax + deformable sampling (l2 slice in LDS)
    msda_sample_v13<<<672, 256, 0, stream>>>(value_bf, comb, refp,
                                             attn_out, sampb);

    // 4. out = sampled @ Wout + bout -> d_out (BN=64: 672 blocks)
    {
        dim3 grid(DD / 64, MTOT / 128);
        gemm_out<<<grid, 256, 0, stream>>>(sampb, Wout_t, bout, out);
    }
}

// Round 18
// 78.188 us; speedup vs baseline: 1.1483x; 1.1483x over previous
//
#include <hip/hip_runtime.h>
#include <hip/hip_bf16.h>
#include <math.h>

// Problem constants (Mask2Former pixel decoder / MS-deformable attention)
#define BB 4
#define SEQ 5376
#define DD 256
#define NH 8
#define NL 3
#define NP 4
#define DH 32
#define MTOT (BB * SEQ)          // 21504 rows for all GEMMs

typedef __attribute__((ext_vector_type(8))) short bf16x8;
typedef __attribute__((ext_vector_type(4))) float f32x4;
typedef __attribute__((ext_vector_type(2))) float f32x2;

#define GLD_LDS16(src, dst) __builtin_amdgcn_global_load_lds( \
    (const __attribute__((address_space(1))) void*)(src),     \
    (__attribute__((address_space(3))) void*)(dst), 16, 0, 0)

__device__ __forceinline__ ushort f2b(float f) {
    __hip_bfloat16 h = __float2bfloat16(f);
    return *reinterpret_cast<ushort*>(&h);
}

// ---------------------------------------------------------------------------
// Fused prep: blocks [0,800] transpose weights -> Wt[800][256] bf16 (+bias
// combine at block 800); blocks [801, 801+2048) convert hidden -> bf16 and
// (hidden+pos) -> bf16 (grid-stride).
// ---------------------------------------------------------------------------
__global__ __launch_bounds__(256) void prep_all(
    const float* __restrict__ hidden, const float* __restrict__ pos,
    const float* __restrict__ Wv, const float* __restrict__ Wo,
    const float* __restrict__ Wa, const float* __restrict__ Wout,
    const float* __restrict__ bo, const float* __restrict__ ba,
    ushort4* __restrict__ hb, ushort4* __restrict__ hsb,
    ushort* __restrict__ Wt, float* __restrict__ bcomb, int n4) {
    int bid = blockIdx.x;
    int tid = threadIdx.x;
    if (bid <= 800) {
        if (bid == 800) {
            for (int i = tid; i < 288; i += 256)
                bcomb[i] = (i < 192) ? bo[i] : ba[i - 192];
            return;
        }
        int row = bid;
        const float* src;
        int N, n;
        if (row < 256)      { src = Wv;   N = 256; n = row; }
        else if (row < 448) { src = Wo;   N = 192; n = row - 256; }
        else if (row < 544) { src = Wa;   N = 96;  n = row - 448; }
        else                { src = Wout; N = 256; n = row - 544; }
        float v = src[(size_t)tid * N + n];
        Wt[(size_t)row * 256 + tid] = f2b(v);
        return;
    }
    // activation conversion
    const float4* h4 = (const float4*)hidden;
    const float4* p4 = (const float4*)pos;
    int i = (bid - 801) * 256 + tid;
    int stride = (gridDim.x - 801) * 256;
    for (; i < n4; i += stride) {
        float4 a = h4[i], b = p4[i];
        ushort4 ua, us;
        ua.x = f2b(a.x); ua.y = f2b(a.y); ua.z = f2b(a.z); ua.w = f2b(a.w);
        us.x = f2b(a.x + b.x); us.y = f2b(a.y + b.y);
        us.z = f2b(a.z + b.z); us.w = f2b(a.w + b.w);
        hb[i] = ua;
        hsb[i] = us;
    }
}

// ---------------------------------------------------------------------------
// Dual bf16 MFMA GEMM (one dispatch = value GEMM + comb GEMM for grid fill).
// Blocks [0,336): value = hb @ Wv^T + bv -> bf16 HEAD-MAJOR [h][row][32ch].
// Blocks [336,840): comb = hsb @ Wcomb^T + bcomb -> fp32, N=288.
// BM=128, BN=128, BK=64; global_load_lds staging, chunk-XOR swizzle both
// sides (R13-proven). 256 thr = 4 waves 2x2; 32 MFMA/wave per barrier pair.
// ---------------------------------------------------------------------------
__global__ __launch_bounds__(256) void gemm_dual(
    const ushort* __restrict__ hb, const ushort* __restrict__ hsb,
    const ushort* __restrict__ Wv_t, const ushort* __restrict__ Wcomb_t,
    const float* __restrict__ bv, const float* __restrict__ bcomb,
    ushort* __restrict__ value_bf, float* __restrict__ comb) {
    const int K = 256, BK = 64;
    __shared__ ushort As[128 * 64];
    __shared__ ushort Bs[128 * 64];

    int b = blockIdx.x;
    const ushort* A;
    const ushort* W;
    const float* bias;
    int bn, bm, N;
    bool obf;
    if (b < 336) {
        A = hb;  W = Wv_t;    bias = bv;    N = 256; obf = true;
        bn = (b & 1) * 128;   bm = (b >> 1) * 128;
    } else {
        int bb = b - 336;
        A = hsb; W = Wcomb_t; bias = bcomb; N = 288; obf = false;
        bn = (bb % 3) * 128;  bm = (bb / 3) * 128;
    }

    int tid = threadIdx.x;
    int lane = tid & 63;
    int wid = tid >> 6;
    int wr = wid >> 1, wc = wid & 1;
    int lr = lane & 15;
    int kg = lane >> 4;

    f32x4 acc[4][4] = {};

    for (int k0 = 0; k0 < K; k0 += BK) {
        #pragma unroll
        for (int c = 0; c < 4; c++) {
            int e = tid + 256 * c;           // chunk id 0..1023
            int row = e >> 3;
            int ch = e & 7;
            int gch = ch ^ (row & 7);
            GLD_LDS16(A + (size_t)(bm + row) * K + k0 + 8 * gch, &As[e * 8]);
            GLD_LDS16(W + (size_t)(bn + row) * K + k0 + 8 * gch, &Bs[e * 8]);
        }
        __syncthreads();
        #pragma unroll
        for (int ks = 0; ks < 2; ks++) {
            bf16x8 af[4], bfr[4];
            #pragma unroll
            for (int mf = 0; mf < 4; mf++) {
                int R = wr * 64 + mf * 16 + lr;
                int sc = (ks * 4 + kg) ^ (R & 7);
                af[mf] = *(bf16x8*)&As[R * 64 + sc * 8];
            }
            #pragma unroll
            for (int nf = 0; nf < 4; nf++) {
                int R = wc * 64 + nf * 16 + lr;
                int sc = (ks * 4 + kg) ^ (R & 7);
                bfr[nf] = *(bf16x8*)&Bs[R * 64 + sc * 8];
            }
            #pragma unroll
            for (int mf = 0; mf < 4; mf++)
                #pragma unroll
                for (int nf = 0; nf < 4; nf++)
                    acc[mf][nf] = __builtin_amdgcn_mfma_f32_16x16x32_bf16(
                        af[mf], bfr[nf], acc[mf][nf], 0, 0, 0);
        }
        __syncthreads();
    }

    #pragma unroll
    for (int nf = 0; nf < 4; nf++) {
        int gc = bn + wc * 64 + nf * 16 + lr;
        if (gc >= N) continue;
        float bvv = bias[gc];
        #pragma unroll
        for (int mf = 0; mf < 4; mf++) {
            int gr0 = bm + wr * 64 + mf * 16 + kg * 4;
            #pragma unroll
            for (int r = 0; r < 4; r++) {
                float v = acc[mf][nf][r] + bvv;
                if (obf) {
                    // head-major scatter: [h][row][32ch]
                    int hh = gc >> 5, cc = gc & 31;
                    value_bf[(size_t)hh * ((size_t)MTOT * 32)
                             + (size_t)(gr0 + r) * 32 + cc] = f2b(v);
                } else {
                    comb[(size_t)(gr0 + r) * 288 + gc] = v;
                }
            }
        }
    }
}

// ---------------------------------------------------------------------------
// Output GEMM: out = sampb @ Wout^T + bout, N=256, fp32 out.
// BM=128, BN=64 (672 blocks for grid fill), BK=64; gld_lds + XOR swizzle.
// ---------------------------------------------------------------------------
__global__ __launch_bounds__(256) void gemm_out(
    const ushort* __restrict__ A, const ushort* __restrict__ Wt,
    const float* __restrict__ bias, float* __restrict__ C) {
    const int K = 256, BK = 64;
    __shared__ ushort As[128 * 64];
    __shared__ ushort Bs[64 * 64];
    int bm = blockIdx.y * 128;
    int bn = blockIdx.x * 64;
    int tid = threadIdx.x;
    int lane = tid & 63;
    int wid = tid >> 6;
    int wr = wid >> 1, wc = wid & 1;
    int lr = lane & 15;
    int kg = lane >> 4;

    f32x4 acc[4][2] = {};

    for (int k0 = 0; k0 < K; k0 += BK) {
        #pragma unroll
        for (int c = 0; c < 4; c++) {
            int e = tid + 256 * c;
            int row = e >> 3;
            int ch = e & 7;
            int gch = ch ^ (row & 7);
            GLD_LDS16(A + (size_t)(bm + row) * K + k0 + 8 * gch, &As[e * 8]);
        }
        #pragma unroll
        for (int c = 0; c < 2; c++) {
            int e = tid + 256 * c;           // 0..511
            int row = e >> 3;                // 0..63
            int ch = e & 7;
            int gch = ch ^ (row & 7);
            GLD_LDS16(Wt + (size_t)(bn + row) * K + k0 + 8 * gch, &Bs[e * 8]);
        }
        __syncthreads();
        #pragma unroll
        for (int ks = 0; ks < 2; ks++) {
            bf16x8 af[4], bfr[2];
            #pragma unroll
            for (int mf = 0; mf < 4; mf++) {
                int R = wr * 64 + mf * 16 + lr;
                int sc = (ks * 4 + kg) ^ (R & 7);
                af[mf] = *(bf16x8*)&As[R * 64 + sc * 8];
            }
            #pragma unroll
            for (int nf = 0; nf < 2; nf++) {
                int R = wc * 32 + nf * 16 + lr;
                int sc = (ks * 4 + kg) ^ (R & 7);
                bfr[nf] = *(bf16x8*)&Bs[R * 64 + sc * 8];
            }
            #pragma unroll
            for (int mf = 0; mf < 4; mf++)
                #pragma unroll
                for (int nf = 0; nf < 2; nf++)
                    acc[mf][nf] = __builtin_amdgcn_mfma_f32_16x16x32_bf16(
                        af[mf], bfr[nf], acc[mf][nf], 0, 0, 0);
        }
        __syncthreads();
    }

    #pragma unroll
    for (int nf = 0; nf < 2; nf++) {
        int gc = bn + wc * 32 + nf * 16 + lr;
        float bvv = bias[gc];
        #pragma unroll
        for (int mf = 0; mf < 4; mf++) {
            int gr0 = bm + wr * 64 + mf * 16 + kg * 4;
            #pragma unroll
            for (int r = 0; r < 4; r++) {
                C[(size_t)(gr0 + r) * 256 + gc] = acc[mf][nf][r] + bvv;
            }
        }
    }
}

// ---------------------------------------------------------------------------
// Deformable sampling v12 (R16 best): head-major value + x-pair loads.
// Block = 128 threads = 2 waves = 2 queries (wave = query).
// Lane = h*8 + d8; part = d8>>2 selects x-slot {px, px+1}; c4 = d8&3 the
// channel quad (8 ch, 16B). Per tap: 2 loads (y0-pair-row, y1-pair-row),
// 128B-contiguous per (h, row); shfl_xor(4) combines the x-parts at the end.
// All loads in-bounds: pair base px = clamp(x0, 0, Wl-2).
// ---------------------------------------------------------------------------
__device__ __forceinline__ void fma8p(f32x2 acc[4], float wt, uint4 u) {
    f32x2 w2 = {wt, wt};
    f32x2 v0, v1, v2, v3;
    v0[0] = __uint_as_float(u.x << 16); v0[1] = __uint_as_float(u.x & 0xffff0000u);
    v1[0] = __uint_as_float(u.y << 16); v1[1] = __uint_as_float(u.y & 0xffff0000u);
    v2[0] = __uint_as_float(u.z << 16); v2[1] = __uint_as_float(u.z & 0xffff0000u);
    v3[0] = __uint_as_float(u.w << 16); v3[1] = __uint_as_float(u.w & 0xffff0000u);
    acc[0] = __builtin_elementwise_fma(v0, w2, acc[0]);
    acc[1] = __builtin_elementwise_fma(v1, w2, acc[1]);
    acc[2] = __builtin_elementwise_fma(v2, w2, acc[2]);
    acc[3] = __builtin_elementwise_fma(v3, w2, acc[3]);
}

__global__ __launch_bounds__(128) void msda_sample_v12(
    const ushort* __restrict__ value, const float* __restrict__ comb,
    const float* __restrict__ refp, float* __restrict__ attn_out,
    ushort* __restrict__ out) {
    __shared__ int2   s_idx[2][8][13];   // [q][h][lp]: row offsets (elements)
    __shared__ float4 s_w[2][8][13];     // (wA_y0, wB_y0, wA_y1, wB_y1)
    int tid = threadIdx.x;
    int bq0 = blockIdx.x * 2;

    // ---- phase 1: softmax + tap setup (256 slots, 2 passes of 128) ----
    #pragma unroll
    for (int it = 0; it < 2; it++) {
        int t = tid + it * 128;
        int lp = t & 15;
        int qh = t >> 4;                 // 0..15
        int q = qh >> 3, h = qh & 7;
        int bq = bq0 + q;
        bool active = lp < 12;
        const float* crow = comb + (size_t)bq * 288;
        float logit = active ? crow[192 + h * 12 + lp] : -INFINITY;
        float m = logit;
        m = fmaxf(m, __shfl_xor(m, 1, 16));
        m = fmaxf(m, __shfl_xor(m, 2, 16));
        m = fmaxf(m, __shfl_xor(m, 4, 16));
        m = fmaxf(m, __shfl_xor(m, 8, 16));
        float e = active ? expf(logit - m) : 0.f;
        float s = e;
        s += __shfl_xor(s, 1, 16);
        s += __shfl_xor(s, 2, 16);
        s += __shfl_xor(s, 4, 16);
        s += __shfl_xor(s, 8, 16);
        float aw = e / s;
        if (active) {
            attn_out[(size_t)bq * 96 + h * 12 + lp] = aw;
            int l = lp >> 2;
            int b = bq / SEQ;
            int Wl = 64 >> l;
            float fW = (float)Wl;
            float rx = refp[(size_t)bq * 6 + 2 * l];
            float ry = refp[(size_t)bq * 6 + 2 * l + 1];
            float ox = crow[h * 24 + lp * 2];
            float oy = crow[h * 24 + lp * 2 + 1];
            float x = rx * fW + ox - 0.5f;
            float y = ry * fW + oy - 0.5f;
            float x0f = floorf(x), y0f = floorf(y);
            float wx = x - x0f, wy = y - y0f;
            int x0 = (int)x0f, y0 = (int)y0f;
            int x1 = x0 + 1, y1 = y0 + 1;
            float vx0 = (x0 >= 0 && x0 < Wl) ? 1.f : 0.f;
            float vx1 = (x1 >= 0 && x1 < Wl) ? 1.f : 0.f;
            float vy0 = (y0 >= 0 && y0 < Wl) ? 1.f : 0.f;   // square levels
            float vy1 = (y1 >= 0 && y1 < Wl) ? 1.f : 0.f;
            int yc0 = min(max(y0, 0), Wl - 1);
            int yc1 = min(max(y1, 0), Wl - 1);
            int px = min(max(x0, 0), Wl - 2);
            float wxl = (1.f - wx) * vx0;    // weight of corner x0
            float wxh = wx * vx1;            // weight of corner x1
            float wA, wB;
            if (px == x0)      { wA = wxl; wB = wxh; }   // interior
            else if (px == x1) { wA = wxh; wB = 0.f; }   // x0 == -1
            else               { wA = 0.f; wB = wxl; }   // x0 == Wl-1
            float wy0v = aw * (1.f - wy) * vy0;
            float wy1v = aw * wy * vy1;
            int st = (l == 0) ? 0 : ((l == 1) ? 4096 : 5120);
            int rowbase = b * SEQ + st;
            s_idx[q][h][lp] = make_int2((rowbase + yc0 * Wl + px) * 32,
                                        (rowbase + yc1 * Wl + px) * 32);
            s_w[q][h][lp] = make_float4(wA * wy0v, wB * wy0v,
                                        wA * wy1v, wB * wy1v);
        }
    }
    __syncthreads();

    // ---- phase 2: x-pair gathers + packed FMA ----
    int wave = tid >> 6, lane = tid & 63;
    int q = wave;
    int bq = bq0 + q;
    int h = lane >> 3;
    int d8 = lane & 7;
    int part = d8 >> 2;                  // 0: x=px, 1: x=px+1
    int c4 = d8 & 3;                     // channel quad (8 ch)
    const ushort* vb = value + (size_t)h * ((size_t)MTOT * 32)
                       + part * 32 + c4 * 8;

    f32x2 acc[4] = {{0.f, 0.f}, {0.f, 0.f}, {0.f, 0.f}, {0.f, 0.f}};
    #pragma unroll
    for (int lp = 0; lp < 12; lp++) {
        int2 ii = s_idx[q][h][lp];
        float4 ww = s_w[q][h][lp];
        float w0 = part ? ww.y : ww.x;
        float w1 = part ? ww.w : ww.z;
        uint4 u0 = *(const uint4*)(vb + ii.x);
        uint4 u1 = *(const uint4*)(vb + ii.y);
        fma8p(acc, w0, u0);
        fma8p(acc, w1, u1);
    }

    // combine the two x-parts (lane ^ 4 flips `part`, same h/c4)
    #pragma unroll
    for (int i = 0; i < 4; i++) {
        acc[i][0] += __shfl_xor(acc[i][0], 4);
        acc[i][1] += __shfl_xor(acc[i][1], 4);
    }
    if (part == 0) {
        bf16x8 o;
        o[0] = (short)f2b(acc[0][0]); o[1] = (short)f2b(acc[0][1]);
        o[2] = (short)f2b(acc[1][0]); o[3] = (short)f2b(acc[1][1]);
        o[4] = (short)f2b(acc[2][0]); o[5] = (short)f2b(acc[2][1]);
        o[6] = (short)f2b(acc[3][0]); o[7] = (short)f2b(acc[3][1]);
        *(bf16x8*)(out + (size_t)bq * 256 + h * 32 + c4 * 8) = o;
    }
}

// ---------------------------------------------------------------------------
extern "C" void kernel_launch(void* const* d_in, const int* in_sizes, int n_in,
                              void* d_out, int out_size, void* d_ws, size_t ws_size,
                              hipStream_t stream) {
    const float* hidden = (const float*)d_in[0];
    const float* pos    = (const float*)d_in[1];
    const float* refp   = (const float*)d_in[2];
    const float* Wv     = (const float*)d_in[3];
    const float* bv     = (const float*)d_in[4];
    const float* Wo     = (const float*)d_in[5];
    const float* bo     = (const float*)d_in[6];
    const float* Wa     = (const float*)d_in[7];
    const float* ba     = (const float*)d_in[8];
    const float* Wout   = (const float*)d_in[9];
    const float* bout   = (const float*)d_in[10];

    float* out      = (float*)d_out;                       // (B,SEQ,256)
    float* attn_out = out + (size_t)BB * SEQ * DD;         // (B,SEQ,NH,NL,NP)

    const size_t BSD = (size_t)BB * SEQ * DD;              // 5,505,024
    char* w = (char*)d_ws;
    ushort* value_bf = (ushort*)w;  w += BSD * 2;                 // bf16 value (head-major)
    float*  comb     = (float*)w;   w += (size_t)MTOT * 288 * 4;  // off|logits
    ushort* sampb    = (ushort*)w;  w += BSD * 2;                 // bf16 sampled
    ushort* hb       = (ushort*)w;  w += BSD * 2;                 // bf16 hidden
    ushort* hsb      = (ushort*)w;  w += BSD * 2;                 // bf16 hidden+pos
    ushort* Wt       = (ushort*)w;  w += (size_t)800 * 256 * 2;   // bf16 weights^T
    float*  bcomb    = (float*)w;                                 // 288 bias

    // 1. fused prep: weights transpose + activation bf16 conversion
    {
        int n4 = (int)(BSD / 4);
        prep_all<<<801 + 2048, 256, 0, stream>>>(hidden, pos, Wv, Wo, Wa, Wout,
                                                 bo, ba, (ushort4*)hb, (ushort4*)hsb,
                                                 Wt, bcomb, n4);
    }

    const ushort* Wv_t    = Wt;
    const ushort* Wcomb_t = Wt + (size_t)256 * 256;   // rows: 192 Wo + 96 Wa
    const ushort* Wout_t  = Wt + (size_t)544 * 256;

    // 2. fused value+comb GEMMs (840 blocks for grid fill)
    gemm_dual<<<840, 256, 0, stream>>>(hb, hsb, Wv_t, Wcomb_t, bv, bcomb,
                                       value_bf, comb);

    // 3. fused softmax + deformable sampling -> attn_out + sampled bf16
    msda_sample_v12<<<MTOT / 2, 128, 0, stream>>>(value_bf, comb, refp,
                                                  attn_out, sampb);

    // 4. out = sampled @ Wout + bout -> d_out (BN=64: 672 blocks)
    {
        dim3 grid(DD / 64, MTOT / 128);
        gemm_out<<<grid, 256, 0, stream>>>(sampb, Wout_t, bout, out);
    }
}